// Round 1
// baseline (274.508 us; speedup 1.0000x reference)
//
#include <hip/hip_runtime.h>

#define LL  8192   // sequence length
#define CC  2048   // channels
#define FF  128    // inner dim of g@kernel
#define KK  257    // taps
#define KP  260    // padded tap row stride (16B-aligned rows: 260*4=1040, 1040%16==0)
#define PAD 128    // (KK-1)/2
#define TL  32     // l-outputs per thread

// ---------------------------------------------------------------- flag build
__global__ void flag_kernel(const int* __restrict__ Yt, int ny, int* __restrict__ flag) {
    int t = threadIdx.x;
    for (int i = t; i < CC; i += blockDim.x) flag[i] = 0;
    __syncthreads();
    for (int i = t; i < ny; i += blockDim.x) flag[Yt[i]] = 1;
}

// ------------------------------------------------- synapse^T (padded) build
// synP[c*KP + k] = sum_f g[c,f]*kern[f,k], or delta(k==PAD) for flagged c.
__global__ __launch_bounds__(256) void syn_kernel(const float* __restrict__ g,
                                                  const float* __restrict__ kern,
                                                  const int* __restrict__ flag,
                                                  float* __restrict__ synP) {
    const int c0  = blockIdx.x * 4;
    const int tid = threadIdx.x;
    const float* g0 = g + (size_t)(c0 + 0) * FF;   // block-uniform -> scalar loads
    const float* g1 = g + (size_t)(c0 + 1) * FF;
    const float* g2 = g + (size_t)(c0 + 2) * FF;
    const float* g3 = g + (size_t)(c0 + 3) * FF;
    const int fl0 = flag[c0 + 0], fl1 = flag[c0 + 1];
    const int fl2 = flag[c0 + 2], fl3 = flag[c0 + 3];
    for (int kk = tid; kk < KK; kk += 256) {
        float a0 = 0.f, a1 = 0.f, a2 = 0.f, a3 = 0.f;
        #pragma unroll 8
        for (int f = 0; f < FF; ++f) {
            float kv = kern[f * KK + kk];          // coalesced across tid
            a0 += kv * g0[f];
            a1 += kv * g1[f];
            a2 += kv * g2[f];
            a3 += kv * g3[f];
        }
        float dlt = (kk == PAD) ? 1.f : 0.f;
        synP[(size_t)(c0 + 0) * KP + kk] = fl0 ? dlt : a0;
        synP[(size_t)(c0 + 1) * KP + kk] = fl1 ? dlt : a1;
        synP[(size_t)(c0 + 2) * KP + kk] = fl2 ? dlt : a2;
        synP[(size_t)(c0 + 3) * KP + kk] = fl3 ? dlt : a3;
    }
}

// ---------------------------------------------------------- depthwise conv
// Thread: one channel c, TL consecutive outputs starting at l0.
// Sliding window W[TL+16] over x[:,c]; 16 taps per macro-step.
template<bool EDGE>
__device__ __forceinline__ void conv_body(const float* __restrict__ xcol,
                                          const float* __restrict__ srow,
                                          float (&acc)[TL], int lbase) {
    float W[TL + 16];
    #pragma unroll
    for (int j = 0; j < TL + 16; ++j) {
        int idx = lbase + j;
        float v = 0.f;
        if (!EDGE || (unsigned)idx < (unsigned)LL) v = xcol[(size_t)idx * CC];
        W[j] = v;
    }
    for (int s = 0; s < 16; ++s) {
        if (s) {
            #pragma unroll
            for (int j = 0; j < TL; ++j) W[j] = W[j + 16];
            #pragma unroll
            for (int j = 0; j < 16; ++j) {
                int idx = lbase + 16 * s + TL + j;
                float v = 0.f;
                if (!EDGE || (unsigned)idx < (unsigned)LL) v = xcol[(size_t)idx * CC];
                W[TL + j] = v;
            }
        }
        // 16 taps, 4 at a time (float4 tap loads, low register pressure)
        #pragma unroll
        for (int q = 0; q < 4; ++q) {
            float4 sq = *(const float4*)(srow + 16 * s + 4 * q);
            #pragma unroll
            for (int j = 0; j < TL; ++j) acc[j] += W[4 * q + 0 + j] * sq.x;
            #pragma unroll
            for (int j = 0; j < TL; ++j) acc[j] += W[4 * q + 1 + j] * sq.y;
            #pragma unroll
            for (int j = 0; j < TL; ++j) acc[j] += W[4 * q + 2 + j] * sq.z;
            #pragma unroll
            for (int j = 0; j < TL; ++j) acc[j] += W[4 * q + 3 + j] * sq.w;
        }
    }
    // final tap k=256: x[lbase+256+j] == W[16+j] (window already holds it)
    float s256 = srow[256];
    #pragma unroll
    for (int j = 0; j < TL; ++j) acc[j] += W[16 + j] * s256;
}

__global__ __launch_bounds__(256) void conv_kernel(const float* __restrict__ x,
                                                   const float* __restrict__ synP,
                                                   float* __restrict__ out) {
    const int c  = blockIdx.y * blockDim.x + threadIdx.x;
    const int l0 = blockIdx.x * TL;
    const int lbase = l0 - PAD;
    const float* xcol = x + c;                        // x[l,c] = xcol[l*CC]
    const float* srow = synP + (size_t)c * KP;
    float acc[TL];
    #pragma unroll
    for (int j = 0; j < TL; ++j) acc[j] = 0.f;

    const bool interior = (l0 >= PAD) && (l0 + TL + PAD <= LL);
    if (interior) conv_body<false>(xcol, srow, acc, lbase);
    else          conv_body<true>(xcol, srow, acc, lbase);

    float4* o = (float4*)(out + (size_t)c * LL + l0); // 128B-aligned chunk
    #pragma unroll
    for (int q = 0; q < TL / 4; ++q)
        o[q] = make_float4(acc[4 * q + 0], acc[4 * q + 1], acc[4 * q + 2], acc[4 * q + 3]);
}

// ------------------------------------------------------------------- launch
extern "C" void kernel_launch(void* const* d_in, const int* in_sizes, int n_in,
                              void* d_out, int out_size, void* d_ws, size_t ws_size,
                              hipStream_t stream) {
    const float* x    = (const float*)d_in[0];
    const int*   Yt   = (const int*)  d_in[1];
    const float* g    = (const float*)d_in[2];
    const float* kern = (const float*)d_in[3];
    float* out = (float*)d_out;

    float* synP = (float*)d_ws;                                   // CC*KP floats
    int*   flag = (int*)((char*)d_ws + (size_t)CC * KP * sizeof(float));
    const int ny = in_sizes[1];

    flag_kernel<<<1, 256, 0, stream>>>(Yt, ny, flag);
    syn_kernel<<<CC / 4, 256, 0, stream>>>(g, kern, flag, synP);
    conv_kernel<<<dim3(LL / TL, CC / 256), 256, 0, stream>>>(x, synP, out);
}

// Round 2
// 149.907 us; speedup vs baseline: 1.8312x; 1.8312x over previous
//
#include <hip/hip_runtime.h>

#define LL   8192   // sequence length
#define CC   2048   // channels
#define FF   128    // inner dim of g@kernel
#define KK   257    // taps
#define PAD  128    // (KK-1)/2

// ---- bf16 MFMA path constants ----
#define XROW 8448   // padded xbp row: 128 zeros | 8192 data | 128 zeros
#define SROW 320    // synE row: 32 zeros | 257 taps | 31 zeros  (index t+32)
#define NT   18     // K-steps of 16 -> covers K in [0,288); 288-31 = 257 ✓

typedef __bf16 bf16x8 __attribute__((ext_vector_type(8)));
typedef float  f32x16 __attribute__((ext_vector_type(16)));

static __device__ __forceinline__ unsigned short f2bf(float f) {
    unsigned u = __float_as_uint(f);
    u = (u + 0x7fffu + ((u >> 16) & 1u)) >> 16;   // RNE
    return (unsigned short)u;
}

// ============================ bf16 path =====================================

// Build synEb[c][320] bf16: zeros | g[c,:]@kernel[:,k] | zeros, with the
// Yt-row override folded in as a delta kernel (tap=1 at k=128) so the conv
// itself reproduces out[c,l] = x[l,c] for flagged channels.
__global__ __launch_bounds__(256) void synb_kernel(const float* __restrict__ g,
                                                   const float* __restrict__ kern,
                                                   const int* __restrict__ Yt, int ny,
                                                   unsigned short* __restrict__ synEb) {
    __shared__ int sfl[4];
    const int c0 = blockIdx.x * 4;
    const int t  = threadIdx.x;
    if (t < 4) sfl[t] = 0;
    __syncthreads();
    for (int i = t; i < ny; i += 256) {
        int y = Yt[i];
        #pragma unroll
        for (int ii = 0; ii < 4; ++ii) if (y == c0 + ii) sfl[ii] = 1;
    }
    __syncthreads();
    const float* g0 = g + (size_t)(c0 + 0) * FF;
    const float* g1 = g + (size_t)(c0 + 1) * FF;
    const float* g2 = g + (size_t)(c0 + 2) * FF;
    const float* g3 = g + (size_t)(c0 + 3) * FF;
    const int fl0 = sfl[0], fl1 = sfl[1], fl2 = sfl[2], fl3 = sfl[3];
    for (int p = t; p < SROW; p += 256) {
        const int kk = p - 32;
        float a0 = 0.f, a1 = 0.f, a2 = 0.f, a3 = 0.f;
        const bool inr = (kk >= 0) && (kk < KK);
        if (inr) {
            #pragma unroll 8
            for (int f = 0; f < FF; ++f) {
                float kv = kern[f * KK + kk];      // coalesced across p
                a0 += kv * g0[f];
                a1 += kv * g1[f];
                a2 += kv * g2[f];
                a3 += kv * g3[f];
            }
        }
        float dlt = (kk == PAD) ? 1.f : 0.f;
        float v0 = inr ? (fl0 ? dlt : a0) : 0.f;
        float v1 = inr ? (fl1 ? dlt : a1) : 0.f;
        float v2 = inr ? (fl2 ? dlt : a2) : 0.f;
        float v3 = inr ? (fl3 ? dlt : a3) : 0.f;
        synEb[(size_t)(c0 + 0) * SROW + p] = f2bf(v0);
        synEb[(size_t)(c0 + 1) * SROW + p] = f2bf(v1);
        synEb[(size_t)(c0 + 2) * SROW + p] = f2bf(v2);
        synEb[(size_t)(c0 + 3) * SROW + p] = f2bf(v3);
    }
}

// x (L,C) fp32 -> xbp (C, XROW) bf16, transposed + zero-padded.
__global__ __launch_bounds__(256) void xpose_kernel(const float* __restrict__ x,
                                                    unsigned short* __restrict__ xbp) {
    __shared__ float tile[64][65];
    const int l0 = blockIdx.x << 6;      // 128 blocks
    const int c0 = blockIdx.y << 6;      // 32 blocks
    const int t  = threadIdx.x;
    const int cl = t & 63, ls = t >> 6;
    #pragma unroll
    for (int k = 0; k < 16; ++k) {
        int ll = (k << 2) + ls;
        tile[ll][cl] = x[(size_t)(l0 + ll) * CC + c0 + cl];   // 256B/wave
    }
    __syncthreads();
    const int l2 = (t & 31) << 1, cg = t >> 5;
    #pragma unroll
    for (int k = 0; k < 8; ++k) {
        int cc = (k << 3) + cg;
        ushort2 v;
        v.x = f2bf(tile[l2 + 0][cc]);    // LDS stride-65: conflict-free
        v.y = f2bf(tile[l2 + 1][cc]);
        *(ushort2*)(xbp + (size_t)(c0 + cc) * XROW + PAD + l0 + l2) = v;
    }
    // fold the pad zeroing into the edge blocks
    if (blockIdx.x == 0) {
        for (int k = 0; k < 32; ++k) {
            int idx = (k << 8) + t, ch = idx >> 7, p = idx & 127;
            xbp[(size_t)(c0 + ch) * XROW + p] = 0;
        }
    } else if (blockIdx.x == 127) {
        for (int k = 0; k < 32; ++k) {
            int idx = (k << 8) + t, ch = idx >> 7, p = idx & 127;
            xbp[(size_t)(c0 + ch) * XROW + PAD + LL + p] = 0;
        }
    }
}

// Depthwise conv as Toeplitz MFMA. Wave = one channel; 8 l-tiles of 1024
// outputs; B-frags (18 x bf16x8) persistent in VGPRs; A window (1280 bf16)
// double-buffered in LDS with 16B-granule XOR swizzle (conflict-free b128).
__global__ __launch_bounds__(256, 3) void conv_mfma(const unsigned short* __restrict__ xbp,
                                                    const unsigned short* __restrict__ synEb,
                                                    float* __restrict__ out) {
    __shared__ int4 xw[2][4][192];            // 24.0 KB
    __shared__ unsigned short synL[4][SROW];  // 2.5 KB
    const int w  = threadIdx.x >> 6;
    const int ln = threadIdx.x & 63;
    const int c  = (blockIdx.x << 2) + w;
    const int j  = ln & 31;                   // A row i == D col == B col
    const int q  = ln >> 5;

    { // stage synE row (640 B)
        const unsigned short* srow = synEb + (size_t)c * SROW;
        #pragma unroll
        for (int k = 0; k < 5; ++k) synL[w][ln + 64 * k] = srow[ln + 64 * k];
    }

    const unsigned short* xrow = xbp + (size_t)c * XROW;
    int4 st0, st1, st2;
    { // tile-0 staging (160 granules = 1280 elems window [l0, l0+1280))
        const int4* src = (const int4*)xrow;
        st0 = src[ln];
        st1 = src[ln + 64];
        if (ln < 32) st2 = src[ln + 128];
        int g0 = ln,      s0 = g0 ^ ((g0 >> 3) & 7);
        int g1 = ln + 64, s1 = g1 ^ ((g1 >> 3) & 7);
        xw[0][w][s0] = st0;
        xw[0][w][s1] = st1;
        if (ln < 32) { int g2 = ln + 128, s2 = g2 ^ ((g2 >> 3) & 7); xw[0][w][s2] = st2; }
    }
    __syncthreads();

    // build B Toeplitz fragments: B[k=8q+r][j] = synE[16m + 8q + r - j]
    bf16x8 bfrag[NT];
    #pragma unroll
    for (int m = 0; m < NT; ++m) {
        union { unsigned short u[8]; bf16x8 v; } B;
        #pragma unroll
        for (int r = 0; r < 8; ++r)
            B.u[r] = synL[w][16 * m + 8 * q + r - j + 32];
        bfrag[m] = B.v;
    }

    const int gb = 4 * j + q;                 // A granule base: 4*i + q
    float* orow = out + (size_t)c * (size_t)LL + j;

    for (int lt = 0; lt < 8; ++lt) {
        const int buf = lt & 1;
        if (lt < 7) {                          // prefetch next window into regs
            const int4* src = (const int4*)(xrow + ((lt + 1) << 10));
            st0 = src[ln];
            st1 = src[ln + 64];
            if (ln < 32) st2 = src[ln + 128];
        }
        f32x16 acc;
        #pragma unroll
        for (int r = 0; r < 16; ++r) acc[r] = 0.0f;
        #pragma unroll
        for (int m = 0; m < NT; ++m) {
            int gm = gb + 2 * m;
            union { int4 i4; bf16x8 v; } A;
            A.i4 = xw[buf][w][gm ^ ((gm >> 3) & 7)];
            acc = __builtin_amdgcn_mfma_f32_32x32x16_bf16(A.v, bfrag[m], acc, 0, 0, 0);
        }
        float* o = orow + (lt << 10);
        #pragma unroll
        for (int r = 0; r < 16; ++r) {         // D: col=lane&31, row=(r&3)+8(r>>2)+4q
            int row = (r & 3) + ((r >> 2) << 3) + (q << 2);
            o[row << 5] = acc[r];
        }
        if (lt < 7) {                          // commit prefetch to other buffer
            int g0 = ln,      s0 = g0 ^ ((g0 >> 3) & 7);
            int g1 = ln + 64, s1 = g1 ^ ((g1 >> 3) & 7);
            xw[buf ^ 1][w][s0] = st0;
            xw[buf ^ 1][w][s1] = st1;
            if (ln < 32) { int g2 = ln + 128, s2 = g2 ^ ((g2 >> 3) & 7); xw[buf ^ 1][w][s2] = st2; }
        }
        __syncthreads();
    }
}

// ===================== fp32 fallback (round-1, ws too small) ================
#define KP 260
#define TL 32

__global__ void flag_kernel(const int* __restrict__ Yt, int ny, int* __restrict__ flag) {
    int t = threadIdx.x;
    for (int i = t; i < CC; i += blockDim.x) flag[i] = 0;
    __syncthreads();
    for (int i = t; i < ny; i += blockDim.x) flag[Yt[i]] = 1;
}

__global__ __launch_bounds__(256) void syn_kernel(const float* __restrict__ g,
                                                  const float* __restrict__ kern,
                                                  const int* __restrict__ flag,
                                                  float* __restrict__ synP) {
    const int c0 = blockIdx.x * 4;
    const int tid = threadIdx.x;
    const float* g0 = g + (size_t)(c0 + 0) * FF;
    const float* g1 = g + (size_t)(c0 + 1) * FF;
    const float* g2 = g + (size_t)(c0 + 2) * FF;
    const float* g3 = g + (size_t)(c0 + 3) * FF;
    const int fl0 = flag[c0 + 0], fl1 = flag[c0 + 1];
    const int fl2 = flag[c0 + 2], fl3 = flag[c0 + 3];
    for (int kk = tid; kk < KK; kk += 256) {
        float a0 = 0.f, a1 = 0.f, a2 = 0.f, a3 = 0.f;
        #pragma unroll 8
        for (int f = 0; f < FF; ++f) {
            float kv = kern[f * KK + kk];
            a0 += kv * g0[f]; a1 += kv * g1[f]; a2 += kv * g2[f]; a3 += kv * g3[f];
        }
        float dlt = (kk == PAD) ? 1.f : 0.f;
        synP[(size_t)(c0 + 0) * KP + kk] = fl0 ? dlt : a0;
        synP[(size_t)(c0 + 1) * KP + kk] = fl1 ? dlt : a1;
        synP[(size_t)(c0 + 2) * KP + kk] = fl2 ? dlt : a2;
        synP[(size_t)(c0 + 3) * KP + kk] = fl3 ? dlt : a3;
    }
}

template<bool EDGE>
__device__ __forceinline__ void conv_body(const float* __restrict__ xcol,
                                          const float* __restrict__ srow,
                                          float (&acc)[TL], int lbase) {
    float W[TL + 16];
    #pragma unroll
    for (int jj = 0; jj < TL + 16; ++jj) {
        int idx = lbase + jj;
        float v = 0.f;
        if (!EDGE || (unsigned)idx < (unsigned)LL) v = xcol[(size_t)idx * CC];
        W[jj] = v;
    }
    for (int s = 0; s < 16; ++s) {
        if (s) {
            #pragma unroll
            for (int jj = 0; jj < TL; ++jj) W[jj] = W[jj + 16];
            #pragma unroll
            for (int jj = 0; jj < 16; ++jj) {
                int idx = lbase + 16 * s + TL + jj;
                float v = 0.f;
                if (!EDGE || (unsigned)idx < (unsigned)LL) v = xcol[(size_t)idx * CC];
                W[TL + jj] = v;
            }
        }
        #pragma unroll
        for (int qq = 0; qq < 4; ++qq) {
            float4 sq = *(const float4*)(srow + 16 * s + 4 * qq);
            #pragma unroll
            for (int jj = 0; jj < TL; ++jj) acc[jj] += W[4 * qq + 0 + jj] * sq.x;
            #pragma unroll
            for (int jj = 0; jj < TL; ++jj) acc[jj] += W[4 * qq + 1 + jj] * sq.y;
            #pragma unroll
            for (int jj = 0; jj < TL; ++jj) acc[jj] += W[4 * qq + 2 + jj] * sq.z;
            #pragma unroll
            for (int jj = 0; jj < TL; ++jj) acc[jj] += W[4 * qq + 3 + jj] * sq.w;
        }
    }
    float s256 = srow[256];
    #pragma unroll
    for (int jj = 0; jj < TL; ++jj) acc[jj] += W[16 + jj] * s256;
}

__global__ __launch_bounds__(256) void conv_kernel(const float* __restrict__ x,
                                                   const float* __restrict__ synP,
                                                   float* __restrict__ out) {
    const int c  = blockIdx.y * blockDim.x + threadIdx.x;
    const int l0 = blockIdx.x * TL;
    const int lbase = l0 - PAD;
    const float* xcol = x + c;
    const float* srow = synP + (size_t)c * KP;
    float acc[TL];
    #pragma unroll
    for (int jj = 0; jj < TL; ++jj) acc[jj] = 0.f;
    const bool interior = (l0 >= PAD) && (l0 + TL + PAD <= LL);
    if (interior) conv_body<false>(xcol, srow, acc, lbase);
    else          conv_body<true>(xcol, srow, acc, lbase);
    float4* o = (float4*)(out + (size_t)c * LL + l0);
    #pragma unroll
    for (int qq = 0; qq < TL / 4; ++qq)
        o[qq] = make_float4(acc[4 * qq + 0], acc[4 * qq + 1], acc[4 * qq + 2], acc[4 * qq + 3]);
}

// ------------------------------------------------------------------- launch
extern "C" void kernel_launch(void* const* d_in, const int* in_sizes, int n_in,
                              void* d_out, int out_size, void* d_ws, size_t ws_size,
                              hipStream_t stream) {
    const float* x    = (const float*)d_in[0];
    const int*   Yt   = (const int*)  d_in[1];
    const float* g    = (const float*)d_in[2];
    const float* kern = (const float*)d_in[3];
    float* out = (float*)d_out;
    const int ny = in_sizes[1];

    const size_t xbp_bytes = (size_t)CC * XROW * sizeof(unsigned short); // 34.6 MB
    const size_t syn_bytes = (size_t)CC * SROW * sizeof(unsigned short); // 1.31 MB

    if (ws_size >= xbp_bytes + syn_bytes) {
        unsigned short* xbp   = (unsigned short*)d_ws;
        unsigned short* synEb = (unsigned short*)((char*)d_ws + xbp_bytes);
        synb_kernel<<<CC / 4, 256, 0, stream>>>(g, kern, Yt, ny, synEb);
        xpose_kernel<<<dim3(LL / 64, CC / 64), 256, 0, stream>>>(x, xbp);
        conv_mfma<<<CC / 4, 256, 0, stream>>>(xbp, synEb, out);
    } else {
        float* synP = (float*)d_ws;
        int*   flag = (int*)((char*)d_ws + (size_t)CC * KP * sizeof(float));
        flag_kernel<<<1, 256, 0, stream>>>(Yt, ny, flag);
        syn_kernel<<<CC / 4, 256, 0, stream>>>(g, kern, flag, synP);
        conv_kernel<<<dim3(LL / TL, CC / 256), 256, 0, stream>>>(x, synP, out);
    }
}